// Round 14
// baseline (412.832 us; speedup 1.0000x reference)
//
#include <hip/hip_runtime.h>
#include <stdint.h>

typedef unsigned short u16;
typedef unsigned int u32;
typedef __attribute__((ext_vector_type(8))) short short8;   // 8 bf16 = 4 VGPR
typedef __attribute__((ext_vector_type(4))) short s16x4;
typedef __attribute__((ext_vector_type(4))) float f32x4;
typedef __attribute__((ext_vector_type(16))) float f32x16;
typedef __attribute__((ext_vector_type(4))) int int4v;

#define MFMA16(a,b,c) __builtin_amdgcn_mfma_f32_16x16x32_bf16(a,b,c,0,0,0)
#define MFMA32(a,b,c) __builtin_amdgcn_mfma_f32_32x32x16_bf16(a,b,c,0,0,0)

constexpr int B_ = 4, C_ = 512, N_ = 4096, D_ = 64;  // D_ = CQK = C/8

static __device__ __forceinline__ u16 f2bf(float f) {
    uint32_t u = __builtin_bit_cast(uint32_t, f);
    uint32_t r = (u + 0x7FFFu + ((u >> 16) & 1u)) >> 16;   // RNE
    return (u16)r;
}

// ---------------- prep: Wcat bf16 [640][512] + biascat; Wq/bq pre-scaled by log2(e) ----
__global__ void prep_w(const float* Wq, const float* bq, const float* Wk, const float* bk,
                       const float* Wv, const float* bv, u16* Wcat, float* biascat) {
    const float LOG2E = 1.44269504088896340736f;
    int idx = blockIdx.x * 256 + threadIdx.x;
    if (idx < 640 * 512) {
        int row = idx >> 9, col = idx & 511;
        float w;
        if (row < 64)        w = Wq[row * 512 + col] * LOG2E;
        else if (row < 128)  w = Wk[(row - 64) * 512 + col];
        else                 w = Wv[(row - 128) * 512 + col];
        Wcat[idx] = f2bf(w);
    }
    if (idx < 640) {
        float bb;
        if (idx < 64)        bb = bq[idx] * LOG2E;
        else if (idx < 128)  bb = bk[idx - 64];
        else                 bb = bv[idx - 128];
        biascat[idx] = bb;
    }
}

// ---------------- transpose x [B][C][N] f32 -> xT [B][N][C] bf16 ----------------
__global__ void transpose_x(const float* __restrict__ x, u16* __restrict__ xT) {
    __shared__ float tile[32][33];
    int n0 = blockIdx.x * 32, c0 = blockIdx.y * 32, b = blockIdx.z;
    int tx = threadIdx.x & 31, ty = threadIdx.x >> 5;       // ty 0..7
    const float* xb = x + (size_t)b * C_ * N_;
#pragma unroll
    for (int r = 0; r < 4; r++) {
        int c = ty * 4 + r;
        tile[c][tx] = xb[(size_t)(c0 + c) * N_ + n0 + tx];
    }
    __syncthreads();
    u16* xTb = xT + (size_t)b * N_ * C_;
#pragma unroll
    for (int r = 0; r < 4; r++) {
        int n = ty * 4 + r;
        xTb[(size_t)(n0 + n) * C_ + c0 + tx] = f2bf(tile[tx][n]);
    }
}

// ---------------- projection GEMM: Y[640][4096] = Wcat x X_b^T, per batch --------
// V is stored with a per-16 j-permutation (swap bits 2<->3 of j&15) so attention's
// PV B-fragment (mfma32 k=hi*8+e needs j=crow(e,hi)) is ONE contiguous dwordx4.
__global__ __launch_bounds__(256) void proj_gemm(const u16* __restrict__ Wcat,
                                                 const float* __restrict__ biascat,
                                                 const u16* __restrict__ xT,
                                                 u16* __restrict__ qT, u16* __restrict__ kT,
                                                 u16* __restrict__ v) {
    int b = blockIdx.z;
    int m0 = blockIdx.y * 64;
    int wave = threadIdx.x >> 6, lane = threadIdx.x & 63;
    int n0 = blockIdx.x * 256 + wave * 64;
    int lr = lane & 15, lc = lane >> 4;
    const u16* xTb = xT + (size_t)b * N_ * C_;

    f32x4 acc[4][4] = {};
    short8 aF[4], bF[4], aFn[4], bFn[4];
#pragma unroll
    for (int ma = 0; ma < 4; ma++)
        aF[ma] = *reinterpret_cast<const short8*>(&Wcat[(size_t)(m0 + ma * 16 + lr) * 512 + lc * 8]);
#pragma unroll
    for (int na = 0; na < 4; na++)
        bF[na] = *reinterpret_cast<const short8*>(&xTb[(size_t)(n0 + na * 16 + lr) * 512 + lc * 8]);

    for (int k0 = 0; k0 < 512; k0 += 32) {
        if (k0 < 480) {
            int kn = k0 + 32;
#pragma unroll
            for (int ma = 0; ma < 4; ma++)
                aFn[ma] = *reinterpret_cast<const short8*>(&Wcat[(size_t)(m0 + ma * 16 + lr) * 512 + kn + lc * 8]);
#pragma unroll
            for (int na = 0; na < 4; na++)
                bFn[na] = *reinterpret_cast<const short8*>(&xTb[(size_t)(n0 + na * 16 + lr) * 512 + kn + lc * 8]);
        }
#pragma unroll
        for (int ma = 0; ma < 4; ma++)
#pragma unroll
            for (int na = 0; na < 4; na++)
                acc[ma][na] = MFMA16(aF[ma], bF[na], acc[ma][na]);
#pragma unroll
        for (int t = 0; t < 4; t++) { aF[t] = aFn[t]; bF[t] = bFn[t]; }
    }
#pragma unroll
    for (int ma = 0; ma < 4; ma++) {
#pragma unroll
        for (int r = 0; r < 4; r++) {
            int m = m0 + ma * 16 + lc * 4 + r;
            float bias = biascat[m];
#pragma unroll
            for (int na = 0; na < 4; na++) {
                int n = n0 + na * 16 + lr;
                u16 hv = f2bf(acc[ma][na][r] + bias);
                if (m < 64)
                    qT[((size_t)b * N_ + n) * D_ + m] = hv;
                else if (m < 128)
                    kT[((size_t)b * N_ + n) * D_ + (m - 64)] = hv;
                else {
                    int nl = n & 15;
                    int np = (nl & 3) | ((nl & 4) << 1) | ((nl & 8) >> 1);   // swap j-bits 2<->3
                    v[((size_t)b * C_ + (m - 128)) * (size_t)N_ + (n & ~15) + np] = hv;
                }
            }
        }
    }
}

// ---------------- fused attention: NO LDS in main loop, no barrier, pipelined P ----------------
// R13 measured LDS-busy ~100us of 126us (every wave re-reads the shared K/V tile: x4
// amplification). R14 deletes the LDS round-trip: waves are fully independent (in-register
// P, R13), so K and V stream straight from global (L1/L2, XCD-resident) -- V's j-perm is
// pre-applied in proj_gemm so PV B-fragments are contiguous dwordx4. P is software-
// pipelined across iterations (PA_cur/PA_next named sets, jt unrolled x2): S(t) MFMA+exp
// overlaps PV(t-1) MFMA; no __syncthreads until epilogue. 512 blocks x 256 thr, ~2/CU.
__global__ __launch_bounds__(256, 2) void attn(const u16* __restrict__ qT, const u16* __restrict__ kT,
                                               const u16* __restrict__ v, const float* __restrict__ x,
                                               const float* __restrict__ gamma_p, float* __restrict__ out) {
    int blk = blockIdx.x;               // [0,512)
    int xcd = blk & 7, rest = blk >> 3; // rest in [0,64)
    int b = xcd >> 1;
    int cs = (xcd & 1) + 2 * (rest & 1);    // c-slice 0..3 (XCD L2: 2MB V + 512KB K)
    int itile = rest >> 1;                   // 0..31
    int c0 = cs * 128;
    int ib0 = itile * 128;

    int tid = threadIdx.x;
    int wv = tid >> 6, lane = tid & 63;
    int li = lane & 31, hi = lane >> 5;

    __shared__ char smem[4 * 4608];     // epilogue transpose scratch only

    const u16* qTb = qT + (size_t)b * N_ * D_;
    const u16* kTb = kT + (size_t)b * N_ * D_;
    const u16* vb  = v  + (size_t)b * C_ * N_;

    // Q fragments (B-operand of mfma32: col=li=i, k=hi*8+e), 4 d-chunks of 16
    short8 qf[4];
#pragma unroll
    for (int dc = 0; dc < 4; dc++)
        qf[dc] = *reinterpret_cast<const short8*>(
            &qTb[(size_t)(ib0 + wv * 32 + li) * D_ + dc * 16 + hi * 8]);

    f32x16 acc[4] = {};                 // [ct]: O[i=crow(r,hi)][c=ct*32+li]
    float lsum = 0.f;

    // V row pointers (permuted-j global layout); each includes the +hi*8 fragment shift
    const u16* vrow0 = vb + (size_t)(c0 + 0 * 32 + li) * N_ + hi * 8;
    const u16* vrow1 = vb + (size_t)(c0 + 1 * 32 + li) * N_ + hi * 8;
    const u16* vrow2 = vb + (size_t)(c0 + 2 * 32 + li) * N_ + hi * 8;
    const u16* vrow3 = vb + (size_t)(c0 + 3 * 32 + li) * N_ + hi * 8;

    short8 PA_A[2][2], PA_B[2][2];

    // S phase: K direct from global; produces PA[jc][h] and lsum
    auto S_PHASE = [&](int t, short8 (&PA)[2][2]) {
        int jb = t * 64;
#pragma unroll
        for (int jc = 0; jc < 2; jc++) {
            const u16* kp = kTb + (size_t)(jb + jc * 32 + li) * D_ + hi * 8;
            short8 kf0 = *reinterpret_cast<const short8*>(kp);
            short8 kf1 = *reinterpret_cast<const short8*>(kp + 16);
            short8 kf2 = *reinterpret_cast<const short8*>(kp + 32);
            short8 kf3 = *reinterpret_cast<const short8*>(kp + 48);
            f32x16 S = {};
            S = MFMA32(kf0, qf[0], S);
            S = MFMA32(kf1, qf[1], S);
            S = MFMA32(kf2, qf[2], S);
            S = MFMA32(kf3, qf[3], S);
            float p[16];
#pragma unroll
            for (int r = 0; r < 16; r++) p[r] = __builtin_amdgcn_exp2f(S[r]);
            lsum += (((p[0]+p[1])+(p[2]+p[3]))+((p[4]+p[5])+(p[6]+p[7])))
                  + (((p[8]+p[9])+(p[10]+p[11]))+((p[12]+p[13])+(p[14]+p[15])));
            u32 w[8];
#pragma unroll
            for (int k = 0; k < 8; k++)
                asm("v_cvt_pk_bf16_f32 %0, %1, %2" : "=v"(w[k]) : "v"(p[2 * k]), "v"(p[2 * k + 1]));
            int4v a0 = { (int)w[0], (int)w[1], (int)w[2], (int)w[3] };
            int4v a1 = { (int)w[4], (int)w[5], (int)w[6], (int)w[7] };
            PA[jc][0] = __builtin_bit_cast(short8, a0);   // k-block j = jc*32 + [0,16)
            PA[jc][1] = __builtin_bit_cast(short8, a1);   // k-block j = jc*32 + [16,32)
        }
    };

    // PV phase: V direct from global (permuted layout -> contiguous dwordx4 fragments)
    auto PV_PHASE = [&](int t, short8 (&PA)[2][2]) {
        int jb = t * 64;
#pragma unroll
        for (int jc = 0; jc < 2; jc++) {
            int jo = jb + jc * 32;
            short8 v00 = *reinterpret_cast<const short8*>(vrow0 + jo);
            short8 v01 = *reinterpret_cast<const short8*>(vrow0 + jo + 16);
            short8 v10 = *reinterpret_cast<const short8*>(vrow1 + jo);
            short8 v11 = *reinterpret_cast<const short8*>(vrow1 + jo + 16);
            short8 v20 = *reinterpret_cast<const short8*>(vrow2 + jo);
            short8 v21 = *reinterpret_cast<const short8*>(vrow2 + jo + 16);
            short8 v30 = *reinterpret_cast<const short8*>(vrow3 + jo);
            short8 v31 = *reinterpret_cast<const short8*>(vrow3 + jo + 16);
            acc[0] = MFMA32(PA[jc][0], v00, acc[0]);
            acc[0] = MFMA32(PA[jc][1], v01, acc[0]);
            acc[1] = MFMA32(PA[jc][0], v10, acc[1]);
            acc[1] = MFMA32(PA[jc][1], v11, acc[1]);
            acc[2] = MFMA32(PA[jc][0], v20, acc[2]);
            acc[2] = MFMA32(PA[jc][1], v21, acc[2]);
            acc[3] = MFMA32(PA[jc][0], v30, acc[3]);
            acc[3] = MFMA32(PA[jc][1], v31, acc[3]);
        }
    };

    // ---- pipelined loop: S one tile ahead of PV; no barriers ----
    S_PHASE(0, PA_A);
    for (int tt = 0; tt < 31; tt++) {
        int t = 2 * tt + 1;
        S_PHASE(t, PA_B);
        PV_PHASE(t - 1, PA_A);
        S_PHASE(t + 1, PA_A);
        PV_PHASE(t, PA_B);
    }
    S_PHASE(63, PA_B);
    PV_PHASE(62, PA_A);
    PV_PHASE(63, PA_B);

    // ---- finalize: row sums, normalize, transpose via per-wave LDS, residual ----
    float lfull = lsum + __shfl_xor(lsum, 32);   // full row-sum for i=li
    float g = gamma_p[0];
    float* olds = reinterpret_cast<float*>(smem + wv * 4608);   // [32 c][36] f32 per wave
    const float* xb = x + (size_t)b * C_ * N_;
    float* ob = out + (size_t)b * C_ * N_;
#pragma unroll
    for (int ct = 0; ct < 4; ct++) {
#pragma unroll
        for (int r = 0; r < 16; r++) {
            int crow = (r & 3) + 8 * (r >> 2) + 4 * hi;     // i-local
            float linv = 1.0f / __shfl(lfull, crow);
            olds[li * 36 + crow] = g * acc[ct][r] * linv;
        }
        asm volatile("s_waitcnt lgkmcnt(0)" ::: "memory");
#pragma unroll
        for (int cp = 0; cp < 4; cp++) {
            int c_l = cp * 8 + (lane >> 3);
            int i4 = (lane & 7) * 4;
            float4 o4 = *reinterpret_cast<const float4*>(&olds[c_l * 36 + i4]);
            size_t off = (size_t)(c0 + ct * 32 + c_l) * N_ + ib0 + wv * 32 + i4;
            float4 xv = *reinterpret_cast<const float4*>(&xb[off]);
            float4 ov = { o4.x + xv.x, o4.y + xv.y, o4.z + xv.z, o4.w + xv.w };
            *reinterpret_cast<float4*>(&ob[off]) = ov;
        }
        asm volatile("s_waitcnt lgkmcnt(0)" ::: "memory");
    }
}

extern "C" void kernel_launch(void* const* d_in, const int* in_sizes, int n_in,
                              void* d_out, int out_size, void* d_ws, size_t ws_size,
                              hipStream_t stream) {
    const float* x     = (const float*)d_in[0];
    const float* Wq    = (const float*)d_in[1];
    const float* bq    = (const float*)d_in[2];
    const float* Wk    = (const float*)d_in[3];
    const float* bk    = (const float*)d_in[4];
    const float* Wv    = (const float*)d_in[5];
    const float* bv    = (const float*)d_in[6];
    const float* gamma = (const float*)d_in[7];
    float* out = (float*)d_out;

    char* ws = (char*)d_ws;
    // layout (bytes): xT 16MB | Wcat 640KB | biascat 4KB | qT 2MB | kT 2MB | v 16MB
    u16*   xT      = (u16*)ws;
    u16*   Wcat    = (u16*)(ws + (size_t)16777216);
    float* biascat = (float*)(ws + (size_t)16777216 + 655360);
    u16*   qT      = (u16*)(ws + (size_t)16777216 + 655360 + 4096);
    u16*   kT      = qT + (size_t)B_ * N_ * D_;
    u16*   v       = kT + (size_t)B_ * N_ * D_;

    prep_w<<<1280, 256, 0, stream>>>(Wq, bq, Wk, bk, Wv, bv, Wcat, biascat);
    transpose_x<<<dim3(N_ / 32, C_ / 32, B_), 256, 0, stream>>>(x, xT);
    proj_gemm<<<dim3(N_ / 256, 640 / 64, B_), 256, 0, stream>>>(Wcat, biascat, xT, qT, kT, v);
    attn<<<512, 256, 0, stream>>>(qT, kT, v, x, gamma, out);
}

// Round 15
// 184.195 us; speedup vs baseline: 2.2413x; 2.2413x over previous
//
#include <hip/hip_runtime.h>
#include <stdint.h>

typedef unsigned short u16;
typedef unsigned int u32;
typedef __attribute__((ext_vector_type(8))) short short8;   // 8 bf16 = 4 VGPR
typedef __attribute__((ext_vector_type(4))) short s16x4;
typedef __attribute__((ext_vector_type(4))) float f32x4;
typedef __attribute__((ext_vector_type(16))) float f32x16;
typedef __attribute__((ext_vector_type(4))) int int4v;

#define MFMA16(a,b,c) __builtin_amdgcn_mfma_f32_16x16x32_bf16(a,b,c,0,0,0)
#define MFMA32(a,b,c) __builtin_amdgcn_mfma_f32_32x32x16_bf16(a,b,c,0,0,0)

constexpr int B_ = 4, C_ = 512, N_ = 4096, D_ = 64;  // D_ = CQK = C/8

static __device__ __forceinline__ u16 f2bf(float f) {
    uint32_t u = __builtin_bit_cast(uint32_t, f);
    uint32_t r = (u + 0x7FFFu + ((u >> 16) & 1u)) >> 16;   // RNE
    return (u16)r;
}

// async global->LDS, 16B per lane: dest = lds_base + lane*16 (wave-uniform base),
// src is PER-LANE global address (guide m104/m173-verified semantics)
static __device__ __forceinline__ void gload_lds16(const void* g, void* l) {
    __builtin_amdgcn_global_load_lds(
        (const __attribute__((address_space(1))) u32*)g,
        (__attribute__((address_space(3))) u32*)l, 16, 0, 0);
}

// ---------------- prep: Wcat bf16 [640][512] + biascat; Wq/bq pre-scaled by log2(e) ----
__global__ void prep_w(const float* Wq, const float* bq, const float* Wk, const float* bk,
                       const float* Wv, const float* bv, u16* Wcat, float* biascat) {
    const float LOG2E = 1.44269504088896340736f;
    int idx = blockIdx.x * 256 + threadIdx.x;
    if (idx < 640 * 512) {
        int row = idx >> 9, col = idx & 511;
        float w;
        if (row < 64)        w = Wq[row * 512 + col] * LOG2E;
        else if (row < 128)  w = Wk[(row - 64) * 512 + col];
        else                 w = Wv[(row - 128) * 512 + col];
        Wcat[idx] = f2bf(w);
    }
    if (idx < 640) {
        float bb;
        if (idx < 64)        bb = bq[idx] * LOG2E;
        else if (idx < 128)  bb = bk[idx - 64];
        else                 bb = bv[idx - 128];
        biascat[idx] = bb;
    }
}

// ---------------- transpose x [B][C][N] f32 -> xT [B][N][C] bf16 ----------------
__global__ void transpose_x(const float* __restrict__ x, u16* __restrict__ xT) {
    __shared__ float tile[32][33];
    int n0 = blockIdx.x * 32, c0 = blockIdx.y * 32, b = blockIdx.z;
    int tx = threadIdx.x & 31, ty = threadIdx.x >> 5;       // ty 0..7
    const float* xb = x + (size_t)b * C_ * N_;
#pragma unroll
    for (int r = 0; r < 4; r++) {
        int c = ty * 4 + r;
        tile[c][tx] = xb[(size_t)(c0 + c) * N_ + n0 + tx];
    }
    __syncthreads();
    u16* xTb = xT + (size_t)b * N_ * C_;
#pragma unroll
    for (int r = 0; r < 4; r++) {
        int n = ty * 4 + r;
        xTb[(size_t)(n0 + n) * C_ + c0 + tx] = f2bf(tile[tx][n]);
    }
}

// ---------------- projection GEMM: Y[640][4096] = Wcat x X_b^T, per batch --------
// V is stored with a per-16 j-permutation (swap bits 2<->3 of j&15) so attention's
// PV B-fragment (mfma32 k=hi*8+e needs j=crow(e,hi)) is ONE contiguous dwordx4.
// (R14-verified: passed with absmax 0.0156.)
__global__ __launch_bounds__(256) void proj_gemm(const u16* __restrict__ Wcat,
                                                 const float* __restrict__ biascat,
                                                 const u16* __restrict__ xT,
                                                 u16* __restrict__ qT, u16* __restrict__ kT,
                                                 u16* __restrict__ v) {
    int b = blockIdx.z;
    int m0 = blockIdx.y * 64;
    int wave = threadIdx.x >> 6, lane = threadIdx.x & 63;
    int n0 = blockIdx.x * 256 + wave * 64;
    int lr = lane & 15, lc = lane >> 4;
    const u16* xTb = xT + (size_t)b * N_ * C_;

    f32x4 acc[4][4] = {};
    short8 aF[4], bF[4], aFn[4], bFn[4];
#pragma unroll
    for (int ma = 0; ma < 4; ma++)
        aF[ma] = *reinterpret_cast<const short8*>(&Wcat[(size_t)(m0 + ma * 16 + lr) * 512 + lc * 8]);
#pragma unroll
    for (int na = 0; na < 4; na++)
        bF[na] = *reinterpret_cast<const short8*>(&xTb[(size_t)(n0 + na * 16 + lr) * 512 + lc * 8]);

    for (int k0 = 0; k0 < 512; k0 += 32) {
        if (k0 < 480) {
            int kn = k0 + 32;
#pragma unroll
            for (int ma = 0; ma < 4; ma++)
                aFn[ma] = *reinterpret_cast<const short8*>(&Wcat[(size_t)(m0 + ma * 16 + lr) * 512 + kn + lc * 8]);
#pragma unroll
            for (int na = 0; na < 4; na++)
                bFn[na] = *reinterpret_cast<const short8*>(&xTb[(size_t)(n0 + na * 16 + lr) * 512 + kn + lc * 8]);
        }
#pragma unroll
        for (int ma = 0; ma < 4; ma++)
#pragma unroll
            for (int na = 0; na < 4; na++)
                acc[ma][na] = MFMA16(aF[ma], bF[na], acc[ma][na]);
#pragma unroll
        for (int t = 0; t < 4; t++) { aF[t] = aFn[t]; bF[t] = bFn[t]; }
    }
#pragma unroll
    for (int ma = 0; ma < 4; ma++) {
#pragma unroll
        for (int r = 0; r < 4; r++) {
            int m = m0 + ma * 16 + lc * 4 + r;
            float bias = biascat[m];
#pragma unroll
            for (int na = 0; na < 4; na++) {
                int n = n0 + na * 16 + lr;
                u16 hv = f2bf(acc[ma][na][r] + bias);
                if (m < 64)
                    qT[((size_t)b * N_ + n) * D_ + m] = hv;
                else if (m < 128)
                    kT[((size_t)b * N_ + n) * D_ + (m - 64)] = hv;
                else {
                    int nl = n & 15;
                    int np = (nl & 3) | ((nl & 4) << 1) | ((nl & 8) >> 1);   // swap j-bits 2<->3
                    v[((size_t)b * C_ + (m - 128)) * (size_t)N_ + (n & ~15) + np] = hv;
                }
            }
        }
    }
}

// ---------------- fused attention: R13 structure + plane-major LDS + global_load_lds ----------------
// 512 blocks x 256 thr (4 waves), 2 blocks/CU. Wave owns 32 i x 128 c; in-register P
// (swapped mfma32 + cvt_pk, permuted-V pairing); S duplicated x4 across c-slices.
// R15 deltas vs R13 (theory: 12.7M bank-conflict cycles ~21us + staging regs/instrs):
//  (1) LDS re-laid out as FRAGMENT PLANES: K[plane=2dc+hi][j] 16B, V[plane=jf][c] 16B
//      -> every ds_read_b128 is 32 lanes x contiguous 512B = conflict-free, no swizzle.
//  (2) staging via __builtin_amdgcn_global_load_lds (16B, per-lane src, uniform dest):
//      zero staging VGPRs, zero ds_writes; 6 async loads/wave/jt; counted-drain:
//      STAGE(t+1) -> compute(t) -> vmcnt(0) -> s_barrier (T3 minimum schedule).
__global__ __launch_bounds__(256, 2) void attn(const u16* __restrict__ qT, const u16* __restrict__ kT,
                                               const u16* __restrict__ v, const float* __restrict__ x,
                                               const float* __restrict__ gamma_p, float* __restrict__ out) {
    int blk = blockIdx.x;               // [0,512)
    int xcd = blk & 7, rest = blk >> 3; // rest in [0,64)
    int b = xcd >> 1;
    int cs = (xcd & 1) + 2 * (rest & 1);    // c-slice 0..3 (XCD L2: 2MB V + 512KB K)
    int itile = rest >> 1;                   // 0..31
    int c0 = cs * 128;
    int ib0 = itile * 128;

    int tid = threadIdx.x;
    int wv = tid >> 6, lane = tid & 63;
    int li = lane & 31, hi = lane >> 5;

    __shared__ char smem[49152];        // 2 x (K 8KB + V 16KB); epilogue reuses buf0

    const u16* qTb = qT + (size_t)b * N_ * D_;
    const u16* kTb = kT + (size_t)b * N_ * D_;
    const u16* vb  = v  + (size_t)b * C_ * N_;

    // Q fragments (B-operand of mfma32: col=li=i, k=hi*8+e), 4 d-chunks of 16
    short8 qf[4];
#pragma unroll
    for (int dc = 0; dc < 4; dc++)
        qf[dc] = *reinterpret_cast<const short8*>(
            &qTb[(size_t)(ib0 + wv * 32 + li) * D_ + dc * 16 + hi * 8]);

    f32x16 acc[4] = {};                 // [ct]: O[i=crow(r,hi)][c=ct*32+li]
    float lsum = 0.f;

    // ---- async staging: wave wv stages K planes {2wv,2wv+1}, V planes {2wv,2wv+1}x2 halves ----
    auto STAGE = [&](int t, int buf) {
        int jb = t * 64;
        char* Kb = smem + buf * 24576;
        char* Vb = Kb + 8192;
#pragma unroll
        for (int q = 0; q < 2; q++) {
            int p = 2 * wv + q;                       // K plane: d-elements p*8..p*8+8
            gload_lds16(kTb + (size_t)(jb + lane) * D_ + p * 8, Kb + p * 1024);
        }
#pragma unroll
        for (int q = 0; q < 2; q++) {
            int jf = 2 * wv + q;                      // V plane: j-elements (permuted) jf*8..+8
#pragma unroll
            for (int h = 0; h < 2; h++) {
                int c = h * 64 + lane;
                gload_lds16(vb + (size_t)(c0 + c) * N_ + jb + jf * 8,
                            Vb + jf * 2048 + h * 1024);
            }
        }
    };

    // ---- prologue: stage tile 0, drain, barrier ----
    STAGE(0, 0);
    asm volatile("s_waitcnt vmcnt(0)" ::: "memory");
    __builtin_amdgcn_s_barrier();
    asm volatile("" ::: "memory");

    for (int t = 0; t < 64; t++) {
        int buf = t & 1;
        char* Kb = smem + buf * 24576;
        char* Vb = Kb + 8192;

        if (t < 63) STAGE(t + 1, buf ^ 1);   // async; drained at loop bottom

        // ---- S + exp + pack for both 32-j chunks (wave-local, conflict-free plane reads) ----
        short8 PA[2][2];
#pragma unroll
        for (int jc = 0; jc < 2; jc++) {
            short8 kf0 = *reinterpret_cast<const short8*>(Kb + (0 + hi) * 1024 + (jc * 32 + li) * 16);
            short8 kf1 = *reinterpret_cast<const short8*>(Kb + (2 + hi) * 1024 + (jc * 32 + li) * 16);
            short8 kf2 = *reinterpret_cast<const short8*>(Kb + (4 + hi) * 1024 + (jc * 32 + li) * 16);
            short8 kf3 = *reinterpret_cast<const short8*>(Kb + (6 + hi) * 1024 + (jc * 32 + li) * 16);
            f32x16 S = {};
            S = MFMA32(kf0, qf[0], S);
            S = MFMA32(kf1, qf[1], S);
            S = MFMA32(kf2, qf[2], S);
            S = MFMA32(kf3, qf[3], S);
            float p[16];
#pragma unroll
            for (int r = 0; r < 16; r++) p[r] = __builtin_amdgcn_exp2f(S[r]);
            lsum += (((p[0]+p[1])+(p[2]+p[3]))+((p[4]+p[5])+(p[6]+p[7])))
                  + (((p[8]+p[9])+(p[10]+p[11]))+((p[12]+p[13])+(p[14]+p[15])));
            u32 w[8];
#pragma unroll
            for (int k = 0; k < 8; k++)
                asm("v_cvt_pk_bf16_f32 %0, %1, %2" : "=v"(w[k]) : "v"(p[2 * k]), "v"(p[2 * k + 1]));
            int4v a0 = { (int)w[0], (int)w[1], (int)w[2], (int)w[3] };
            int4v a1 = { (int)w[4], (int)w[5], (int)w[6], (int)w[7] };
            PA[jc][0] = __builtin_bit_cast(short8, a0);
            PA[jc][1] = __builtin_bit_cast(short8, a1);
        }

        // ---- PV: 16 mfma32; V planes match PA's permuted-j order (proj pre-permuted) ----
#pragma unroll
        for (int jc = 0; jc < 2; jc++)
#pragma unroll
            for (int ct = 0; ct < 4; ct++) {
                short8 vf0 = *reinterpret_cast<const short8*>(
                    Vb + (jc * 4 + hi) * 2048 + (ct * 32 + li) * 16);
                short8 vf1 = *reinterpret_cast<const short8*>(
                    Vb + (jc * 4 + 2 + hi) * 2048 + (ct * 32 + li) * 16);
                acc[ct] = MFMA32(PA[jc][0], vf0, acc[ct]);
                acc[ct] = MFMA32(PA[jc][1], vf1, acc[ct]);
            }

        // ---- drain next tile's async loads (issued before ~2K cyc of compute), barrier ----
        asm volatile("s_waitcnt vmcnt(0)" ::: "memory");
        __builtin_amdgcn_s_barrier();
        asm volatile("" ::: "memory");
    }

    // ---- finalize: row sums, normalize, transpose via per-wave LDS, residual ----
    float lfull = lsum + __shfl_xor(lsum, 32);   // full row-sum for i=li
    float g = gamma_p[0];
    float* olds = reinterpret_cast<float*>(smem + wv * 4608);   // [32 c][36] f32 per wave
    const float* xb = x + (size_t)b * C_ * N_;
    float* ob = out + (size_t)b * C_ * N_;
#pragma unroll
    for (int ct = 0; ct < 4; ct++) {
#pragma unroll
        for (int r = 0; r < 16; r++) {
            int crow = (r & 3) + 8 * (r >> 2) + 4 * hi;     // i-local
            float linv = 1.0f / __shfl(lfull, crow);
            olds[li * 36 + crow] = g * acc[ct][r] * linv;
        }
        asm volatile("s_waitcnt lgkmcnt(0)" ::: "memory");
#pragma unroll
        for (int cp = 0; cp < 4; cp++) {
            int c_l = cp * 8 + (lane >> 3);
            int i4 = (lane & 7) * 4;
            float4 o4 = *reinterpret_cast<const float4*>(&olds[c_l * 36 + i4]);
            size_t off = (size_t)(c0 + ct * 32 + c_l) * N_ + ib0 + wv * 32 + i4;
            float4 xv = *reinterpret_cast<const float4*>(&xb[off]);
            float4 ov = { o4.x + xv.x, o4.y + xv.y, o4.z + xv.z, o4.w + xv.w };
            *reinterpret_cast<float4*>(&ob[off]) = ov;
        }
        asm volatile("s_waitcnt lgkmcnt(0)" ::: "memory");
    }
}

extern "C" void kernel_launch(void* const* d_in, const int* in_sizes, int n_in,
                              void* d_out, int out_size, void* d_ws, size_t ws_size,
                              hipStream_t stream) {
    const float* x     = (const float*)d_in[0];
    const float* Wq    = (const float*)d_in[1];
    const float* bq    = (const float*)d_in[2];
    const float* Wk    = (const float*)d_in[3];
    const float* bk    = (const float*)d_in[4];
    const float* Wv    = (const float*)d_in[5];
    const float* bv    = (const float*)d_in[6];
    const float* gamma = (const float*)d_in[7];
    float* out = (float*)d_out;

    char* ws = (char*)d_ws;
    // layout (bytes): xT 16MB | Wcat 640KB | biascat 4KB | qT 2MB | kT 2MB | v 16MB
    u16*   xT      = (u16*)ws;
    u16*   Wcat    = (u16*)(ws + (size_t)16777216);
    float* biascat = (float*)(ws + (size_t)16777216 + 655360);
    u16*   qT      = (u16*)(ws + (size_t)16777216 + 655360 + 4096);
    u16*   kT      = qT + (size_t)B_ * N_ * D_;
    u16*   v       = kT + (size_t)B_ * N_ * D_;

    prep_w<<<1280, 256, 0, stream>>>(Wq, bq, Wk, bk, Wv, bv, Wcat, biascat);
    transpose_x<<<dim3(N_ / 32, C_ / 32, B_), 256, 0, stream>>>(x, xT);
    proj_gemm<<<dim3(N_ / 256, 640 / 64, B_), 256, 0, stream>>>(Wcat, biascat, xT, qT, kT, v);
    attn<<<512, 256, 0, stream>>>(qT, kT, v, x, gamma, out);
}

// Round 16
// 173.352 us; speedup vs baseline: 2.3815x; 1.0625x over previous
//
#include <hip/hip_runtime.h>
#include <stdint.h>

typedef unsigned short u16;
typedef unsigned int u32;
typedef __attribute__((ext_vector_type(8))) short short8;   // 8 bf16 = 4 VGPR
typedef __attribute__((ext_vector_type(4))) short s16x4;
typedef __attribute__((ext_vector_type(4))) float f32x4;
typedef __attribute__((ext_vector_type(16))) float f32x16;
typedef __attribute__((ext_vector_type(4))) int int4v;

#define MFMA16(a,b,c) __builtin_amdgcn_mfma_f32_16x16x32_bf16(a,b,c,0,0,0)
#define MFMA32(a,b,c) __builtin_amdgcn_mfma_f32_32x32x16_bf16(a,b,c,0,0,0)

constexpr int B_ = 4, C_ = 512, N_ = 4096, D_ = 64;  // D_ = CQK = C/8

static __device__ __forceinline__ u16 f2bf(float f) {
    uint32_t u = __builtin_bit_cast(uint32_t, f);
    uint32_t r = (u + 0x7FFFu + ((u >> 16) & 1u)) >> 16;   // RNE
    return (u16)r;
}

// async global->LDS, 16B per lane: dest = lds_base + lane*16 (wave-uniform base),
// src is PER-LANE global address
static __device__ __forceinline__ void gload_lds16(const void* g, void* l) {
    __builtin_amdgcn_global_load_lds(
        (const __attribute__((address_space(1))) u32*)g,
        (__attribute__((address_space(3))) u32*)l, 16, 0, 0);
}

// ---------------- prep: Wcat bf16 [640][512] + biascat; Wq/bq pre-scaled by log2(e) ----
__global__ void prep_w(const float* Wq, const float* bq, const float* Wk, const float* bk,
                       const float* Wv, const float* bv, u16* Wcat, float* biascat) {
    const float LOG2E = 1.44269504088896340736f;
    int idx = blockIdx.x * 256 + threadIdx.x;
    if (idx < 640 * 512) {
        int row = idx >> 9, col = idx & 511;
        float w;
        if (row < 64)        w = Wq[row * 512 + col] * LOG2E;
        else if (row < 128)  w = Wk[(row - 64) * 512 + col];
        else                 w = Wv[(row - 128) * 512 + col];
        Wcat[idx] = f2bf(w);
    }
    if (idx < 640) {
        float bb;
        if (idx < 64)        bb = bq[idx] * LOG2E;
        else if (idx < 128)  bb = bk[idx - 64];
        else                 bb = bv[idx - 128];
        biascat[idx] = bb;
    }
}

// ---------------- transpose x [B][C][N] f32 -> xT [B][N][C] bf16 (64x64, vectorized) ----
__global__ __launch_bounds__(256) void transpose_x(const float* __restrict__ x, u16* __restrict__ xT) {
    __shared__ float tile[64][65];
    int n0 = blockIdx.x * 64, c0 = blockIdx.y * 64, b = blockIdx.z;
    int t = threadIdx.x;
    int colq = (t & 15) * 4, rowb = t >> 4;      // rowb 0..15
    const float* xb = x + (size_t)b * C_ * N_;
#pragma unroll
    for (int k = 0; k < 4; k++) {
        int row = rowb + 16 * k;                 // c-row
        float4 xv = *reinterpret_cast<const float4*>(&xb[(size_t)(c0 + row) * N_ + n0 + colq]);
        tile[row][colq + 0] = xv.x;
        tile[row][colq + 1] = xv.y;
        tile[row][colq + 2] = xv.z;
        tile[row][colq + 3] = xv.w;
    }
    __syncthreads();
    u16* xTb = xT + (size_t)b * N_ * C_;
#pragma unroll
    for (int k = 0; k < 4; k++) {
        int n = rowb + 16 * k;
        ushort4 o;
        o.x = f2bf(tile[colq + 0][n]);
        o.y = f2bf(tile[colq + 1][n]);
        o.z = f2bf(tile[colq + 2][n]);
        o.w = f2bf(tile[colq + 3][n]);
        *reinterpret_cast<ushort4*>(&xTb[(size_t)(n0 + n) * C_ + c0 + colq]) = o;
    }
}

// ---------------- projection GEMM: Y[640][4096] = Wcat x X_b^T, XCD-swizzled --------
// V stored with per-16 j-permutation (swap bits 2<->3 of j&15) so attention's PV
// B-fragment is ONE contiguous dwordx4 (R14/R15-verified).
// Grid 640 linear; decode maps batch b -> XCD pair {2b,2b+1} so each XCD's L2 holds
// one 4MB xT panel (default round-robin replicated it across all 8 L2s).
__global__ __launch_bounds__(256) void proj_gemm(const u16* __restrict__ Wcat,
                                                 const float* __restrict__ biascat,
                                                 const u16* __restrict__ xT,
                                                 u16* __restrict__ qT, u16* __restrict__ kT,
                                                 u16* __restrict__ v) {
    int wg = blockIdx.x;                 // [0,640)
    int xcd = wg & 7, slot = wg >> 3;    // slot 0..79
    int b = xcd >> 1;
    int m0 = (slot >> 3) * 64;                       // 10 m-tiles
    int n0 = ((xcd & 1) * 8 + (slot & 7)) * 256;     // 16 n-tiles
    int wave = threadIdx.x >> 6, lane = threadIdx.x & 63;
    n0 += wave * 64;
    int lr = lane & 15, lc = lane >> 4;
    const u16* xTb = xT + (size_t)b * N_ * C_;

    f32x4 acc[4][4] = {};
    short8 aF[4], bF[4], aFn[4], bFn[4];
#pragma unroll
    for (int ma = 0; ma < 4; ma++)
        aF[ma] = *reinterpret_cast<const short8*>(&Wcat[(size_t)(m0 + ma * 16 + lr) * 512 + lc * 8]);
#pragma unroll
    for (int na = 0; na < 4; na++)
        bF[na] = *reinterpret_cast<const short8*>(&xTb[(size_t)(n0 + na * 16 + lr) * 512 + lc * 8]);

    for (int k0 = 0; k0 < 512; k0 += 32) {
        if (k0 < 480) {
            int kn = k0 + 32;
#pragma unroll
            for (int ma = 0; ma < 4; ma++)
                aFn[ma] = *reinterpret_cast<const short8*>(&Wcat[(size_t)(m0 + ma * 16 + lr) * 512 + kn + lc * 8]);
#pragma unroll
            for (int na = 0; na < 4; na++)
                bFn[na] = *reinterpret_cast<const short8*>(&xTb[(size_t)(n0 + na * 16 + lr) * 512 + kn + lc * 8]);
        }
#pragma unroll
        for (int ma = 0; ma < 4; ma++)
#pragma unroll
            for (int na = 0; na < 4; na++)
                acc[ma][na] = MFMA16(aF[ma], bF[na], acc[ma][na]);
#pragma unroll
        for (int t = 0; t < 4; t++) { aF[t] = aFn[t]; bF[t] = bFn[t]; }
    }
#pragma unroll
    for (int ma = 0; ma < 4; ma++) {
#pragma unroll
        for (int r = 0; r < 4; r++) {
            int m = m0 + ma * 16 + lc * 4 + r;
            float bias = biascat[m];
#pragma unroll
            for (int na = 0; na < 4; na++) {
                int n = n0 + na * 16 + lr;
                u16 hv = f2bf(acc[ma][na][r] + bias);
                if (m < 64)
                    qT[((size_t)b * N_ + n) * D_ + m] = hv;
                else if (m < 128)
                    kT[((size_t)b * N_ + n) * D_ + (m - 64)] = hv;
                else {
                    int nl = n & 15;
                    int np = (nl & 3) | ((nl & 4) << 1) | ((nl & 8) >> 1);   // swap j-bits 2<->3
                    v[((size_t)b * C_ + (m - 128)) * (size_t)N_ + (n & ~15) + np] = hv;
                }
            }
        }
    }
}

// ---------------- fused attention: plane-LDS + async staging, TILE_J=128, 8-wave block ----------------
// 256 blocks x 512 thr (8 waves), 1 block/CU (2 waves/SIMD). Wave owns 32 i x 128 c;
// in-register P (swapped mfma32 + cvt_pk, permuted-V pairing); S dup x4 across c-slices.
// R16 delta vs R15: j-tile 64 -> 128 (barriers 64 -> 32, staging instrs per j halved,
// 4 jc-chains per tile for ILP). LDS fragment planes (conflict-free by construction):
// K[plane=2dc+hi][j] 16B-contig, V[plane=2*(2jc+h)+hi][c] 16B-contig; staged via
// global_load_lds (per-lane src, uniform dest), drained once per tile (vmcnt(0)+barrier).
__global__ __launch_bounds__(512, 2) void attn(const u16* __restrict__ qT, const u16* __restrict__ kT,
                                               const u16* __restrict__ v, const float* __restrict__ x,
                                               const float* __restrict__ gamma_p, float* __restrict__ out) {
    int blk = blockIdx.x;               // [0,256)
    int xcd = blk & 7, rest = blk >> 3; // rest in [0,32)
    int b = xcd >> 1;
    int cs = (xcd & 1) + 2 * (rest & 1);    // c-slice 0..3 (XCD L2: 2MB V + 512KB K)
    int itile = rest >> 1;                   // 0..15
    int c0 = cs * 128;
    int ib0 = itile * 256;

    int tid = threadIdx.x;
    int wv = tid >> 6, lane = tid & 63;
    int li = lane & 31, hi = lane >> 5;

    __shared__ char smem[98304];        // 2 x (K 16KB + V 32KB); epilogue reuses

    const u16* qTb = qT + (size_t)b * N_ * D_;
    const u16* kTb = kT + (size_t)b * N_ * D_;
    const u16* vb  = v  + (size_t)b * C_ * N_;

    // Q fragments (B-operand of mfma32: col=li=i, k=hi*8+e), 4 d-chunks of 16
    short8 qf[4];
#pragma unroll
    for (int dc = 0; dc < 4; dc++)
        qf[dc] = *reinterpret_cast<const short8*>(
            &qTb[(size_t)(ib0 + wv * 32 + li) * D_ + dc * 16 + hi * 8]);

    f32x16 acc[4] = {};                 // [ct]: O[i=crow(r,hi)][c=ct*32+li]
    float lsum = 0.f;

    // ---- async staging: 6 loads/wave per 128-j tile (K:2, V:4) ----
    auto STAGE = [&](int t, int buf) {
        int jb = t * 128;
        char* Kb = smem + buf * 49152;
        char* Vb = Kb + 16384;
#pragma unroll
        for (int q = 0; q < 2; q++) {
            int ki = 2 * wv + q;                      // 0..15
            int p = ki >> 1, jh2 = ki & 1;            // K plane p (d-octet), j-half
            gload_lds16(kTb + (size_t)(jb + jh2 * 64 + lane) * D_ + p * 8,
                        Kb + p * 2048 + jh2 * 1024);
        }
#pragma unroll
        for (int q = 0; q < 4; q++) {
            int vi = 4 * wv + q;                      // 0..31
            int qp = vi >> 1, ch = vi & 1;            // V plane qp (j16b,hb), c-half
            int j16b = qp >> 1, hb = qp & 1;
            gload_lds16(vb + (size_t)(c0 + ch * 64 + lane) * N_ + jb + j16b * 16 + hb * 8,
                        Vb + qp * 2048 + ch * 1024);
        }
    };

    // ---- prologue: stage tile 0, drain, barrier ----
    STAGE(0, 0);
    asm volatile("s_waitcnt vmcnt(0)" ::: "memory");
    __builtin_amdgcn_s_barrier();
    asm volatile("" ::: "memory");

    for (int t = 0; t < 32; t++) {
        int buf = t & 1;
        char* Kb = smem + buf * 49152;
        char* Vb = Kb + 16384;

        if (t < 31) STAGE(t + 1, buf ^ 1);   // async; drained at loop bottom

        // ---- per 32-j chunk: S (4 MFMA) -> exp/pack -> PV (8 MFMA); 4 chunks/tile ----
#pragma unroll
        for (int jc = 0; jc < 4; jc++) {
            short8 kf0 = *reinterpret_cast<const short8*>(Kb + (0 + hi) * 2048 + (jc * 32 + li) * 16);
            short8 kf1 = *reinterpret_cast<const short8*>(Kb + (2 + hi) * 2048 + (jc * 32 + li) * 16);
            short8 kf2 = *reinterpret_cast<const short8*>(Kb + (4 + hi) * 2048 + (jc * 32 + li) * 16);
            short8 kf3 = *reinterpret_cast<const short8*>(Kb + (6 + hi) * 2048 + (jc * 32 + li) * 16);
            f32x16 S = {};
            S = MFMA32(kf0, qf[0], S);
            S = MFMA32(kf1, qf[1], S);
            S = MFMA32(kf2, qf[2], S);
            S = MFMA32(kf3, qf[3], S);
            float p[16];
#pragma unroll
            for (int r = 0; r < 16; r++) p[r] = __builtin_amdgcn_exp2f(S[r]);
            lsum += (((p[0]+p[1])+(p[2]+p[3]))+((p[4]+p[5])+(p[6]+p[7])))
                  + (((p[8]+p[9])+(p[10]+p[11]))+((p[12]+p[13])+(p[14]+p[15])));
            u32 w[8];
#pragma unroll
            for (int k = 0; k < 8; k++)
                asm("v_cvt_pk_bf16_f32 %0, %1, %2" : "=v"(w[k]) : "v"(p[2 * k]), "v"(p[2 * k + 1]));
            int4v a0 = { (int)w[0], (int)w[1], (int)w[2], (int)w[3] };
            int4v a1 = { (int)w[4], (int)w[5], (int)w[6], (int)w[7] };
            short8 PA0 = __builtin_bit_cast(short8, a0);
            short8 PA1 = __builtin_bit_cast(short8, a1);
#pragma unroll
            for (int ct = 0; ct < 4; ct++) {
                short8 vf0 = *reinterpret_cast<const short8*>(
                    Vb + ((jc * 2 + 0) * 2 + hi) * 2048 + (ct * 32 + li) * 16);
                short8 vf1 = *reinterpret_cast<const short8*>(
                    Vb + ((jc * 2 + 1) * 2 + hi) * 2048 + (ct * 32 + li) * 16);
                acc[ct] = MFMA32(PA0, vf0, acc[ct]);
                acc[ct] = MFMA32(PA1, vf1, acc[ct]);
            }
        }

        // ---- drain next tile's async loads, barrier (once per 128 j) ----
        asm volatile("s_waitcnt vmcnt(0)" ::: "memory");
        __builtin_amdgcn_s_barrier();
        asm volatile("" ::: "memory");
    }

    // ---- finalize: row sums, normalize, transpose via per-wave LDS, residual ----
    float lfull = lsum + __shfl_xor(lsum, 32);   // full row-sum for i=li
    float g = gamma_p[0];
    float* olds = reinterpret_cast<float*>(smem + wv * 4608);   // [32 c][36] f32 per wave
    const float* xb = x + (size_t)b * C_ * N_;
    float* ob = out + (size_t)b * C_ * N_;
#pragma unroll
    for (int ct = 0; ct < 4; ct++) {
#pragma unroll
        for (int r = 0; r < 16; r++) {
            int crow = (r & 3) + 8 * (r >> 2) + 4 * hi;     // i-local
            float linv = 1.0f / __shfl(lfull, crow);
            olds[li * 36 + crow] = g * acc[ct][r] * linv;
        }
        asm volatile("s_waitcnt lgkmcnt(0)" ::: "memory");
#pragma unroll
        for (int cp = 0; cp < 4; cp++) {
            int c_l = cp * 8 + (lane >> 3);
            int i4 = (lane & 7) * 4;
            float4 o4 = *reinterpret_cast<const float4*>(&olds[c_l * 36 + i4]);
            size_t off = (size_t)(c0 + ct * 32 + c_l) * N_ + ib0 + wv * 32 + i4;
            float4 xv = *reinterpret_cast<const float4*>(&xb[off]);
            float4 ov = { o4.x + xv.x, o4.y + xv.y, o4.z + xv.z, o4.w + xv.w };
            *reinterpret_cast<float4*>(&ob[off]) = ov;
        }
        asm volatile("s_waitcnt lgkmcnt(0)" ::: "memory");
    }
}

extern "C" void kernel_launch(void* const* d_in, const int* in_sizes, int n_in,
                              void* d_out, int out_size, void* d_ws, size_t ws_size,
                              hipStream_t stream) {
    const float* x     = (const float*)d_in[0];
    const float* Wq    = (const float*)d_in[1];
    const float* bq    = (const float*)d_in[2];
    const float* Wk    = (const float*)d_in[3];
    const float* bk    = (const float*)d_in[4];
    const float* Wv    = (const float*)d_in[5];
    const float* bv    = (const float*)d_in[6];
    const float* gamma = (const float*)d_in[7];
    float* out = (float*)d_out;

    char* ws = (char*)d_ws;
    // layout (bytes): xT 16MB | Wcat 640KB | biascat 4KB | qT 2MB | kT 2MB | v 16MB
    u16*   xT      = (u16*)ws;
    u16*   Wcat    = (u16*)(ws + (size_t)16777216);
    float* biascat = (float*)(ws + (size_t)16777216 + 655360);
    u16*   qT      = (u16*)(ws + (size_t)16777216 + 655360 + 4096);
    u16*   kT      = qT + (size_t)B_ * N_ * D_;
    u16*   v       = kT + (size_t)B_ * N_ * D_;

    prep_w<<<1280, 256, 0, stream>>>(Wq, bq, Wk, bk, Wv, bv, Wcat, biascat);
    transpose_x<<<dim3(N_ / 64, C_ / 64, B_), 256, 0, stream>>>(x, xT);
    proj_gemm<<<640, 256, 0, stream>>>(Wcat, biascat, xT, qT, kT, v);
    attn<<<256, 512, 0, stream>>>(qT, kT, v, x, gamma, out);
}

// Round 17
// 169.135 us; speedup vs baseline: 2.4408x; 1.0249x over previous
//
#include <hip/hip_runtime.h>
#include <stdint.h>

typedef unsigned short u16;
typedef unsigned int u32;
typedef __attribute__((ext_vector_type(8))) short short8;   // 8 bf16 = 4 VGPR
typedef __attribute__((ext_vector_type(4))) short s16x4;
typedef __attribute__((ext_vector_type(4))) float f32x4;
typedef __attribute__((ext_vector_type(16))) float f32x16;
typedef __attribute__((ext_vector_type(4))) int int4v;

#define MFMA16(a,b,c) __builtin_amdgcn_mfma_f32_16x16x32_bf16(a,b,c,0,0,0)
#define MFMA32(a,b,c) __builtin_amdgcn_mfma_f32_32x32x16_bf16(a,b,c,0,0,0)

constexpr int B_ = 4, C_ = 512, N_ = 4096, D_ = 64;  // D_ = CQK = C/8

static __device__ __forceinline__ u16 f2bf(float f) {
    uint32_t u = __builtin_bit_cast(uint32_t, f);
    uint32_t r = (u + 0x7FFFu + ((u >> 16) & 1u)) >> 16;   // RNE
    return (u16)r;
}

// async global->LDS, 16B per lane: dest = lds_base + lane*16 (wave-uniform base),
// src is PER-LANE global address
static __device__ __forceinline__ void gload_lds16(const void* g, void* l) {
    __builtin_amdgcn_global_load_lds(
        (const __attribute__((address_space(1))) u32*)g,
        (__attribute__((address_space(3))) u32*)l, 16, 0, 0);
}

// ---------------- merged: transpose x (z<B) + prep Wcat/biascat (z==B) ----------------
// transpose: x [B][C][N] f32 -> xT [B][N][C] bf16, 64x64 tiles, vectorized.
// prep: Wcat bf16 [640][512] (q 0-63 *log2e, k 64-127, v 128-639) + biascat.
__global__ __launch_bounds__(256) void prep_and_transpose(
        const float* __restrict__ x, u16* __restrict__ xT,
        const float* __restrict__ Wq, const float* __restrict__ bq,
        const float* __restrict__ Wk, const float* __restrict__ bk,
        const float* __restrict__ Wv, const float* __restrict__ bv,
        u16* __restrict__ Wcat, float* __restrict__ biascat) {
    const float LOG2E = 1.44269504088896340736f;
    if (blockIdx.z == B_) {
        int base = (blockIdx.y * 64 + blockIdx.x) * 256 + threadIdx.x;  // 131072 threads
        for (int idx = base; idx < 640 * 512; idx += 64 * 8 * 256) {
            int row = idx >> 9, col = idx & 511;
            float w;
            if (row < 64)        w = Wq[row * 512 + col] * LOG2E;
            else if (row < 128)  w = Wk[(row - 64) * 512 + col];
            else                 w = Wv[(row - 128) * 512 + col];
            Wcat[idx] = f2bf(w);
        }
        if (base < 640) {
            float bb;
            if (base < 64)       bb = bq[base] * LOG2E;
            else if (base < 128) bb = bk[base - 64];
            else                 bb = bv[base - 128];
            biascat[base] = bb;
        }
        return;
    }
    __shared__ float tile[64][65];
    int n0 = blockIdx.x * 64, c0 = blockIdx.y * 64, b = blockIdx.z;
    int t = threadIdx.x;
    int colq = (t & 15) * 4, rowb = t >> 4;      // rowb 0..15
    const float* xb = x + (size_t)b * C_ * N_;
#pragma unroll
    for (int k = 0; k < 4; k++) {
        int row = rowb + 16 * k;                 // c-row
        float4 xv = *reinterpret_cast<const float4*>(&xb[(size_t)(c0 + row) * N_ + n0 + colq]);
        tile[row][colq + 0] = xv.x;
        tile[row][colq + 1] = xv.y;
        tile[row][colq + 2] = xv.z;
        tile[row][colq + 3] = xv.w;
    }
    __syncthreads();
    u16* xTb = xT + (size_t)b * N_ * C_;
#pragma unroll
    for (int k = 0; k < 4; k++) {
        int n = rowb + 16 * k;
        ushort4 o;
        o.x = f2bf(tile[colq + 0][n]);
        o.y = f2bf(tile[colq + 1][n]);
        o.z = f2bf(tile[colq + 2][n]);
        o.w = f2bf(tile[colq + 3][n]);
        *reinterpret_cast<ushort4*>(&xTb[(size_t)(n0 + n) * C_ + c0 + colq]) = o;
    }
}

// ---------------- projection GEMM: Y[640][4096] = Wcat x X_b^T, XCD-swizzled --------
// V stored with per-16 j-permutation (swap bits 2<->3 of j&15) so attention's PV
// B-fragment is ONE contiguous dwordx4 (R14/R15-verified).
__global__ __launch_bounds__(256) void proj_gemm(const u16* __restrict__ Wcat,
                                                 const float* __restrict__ biascat,
                                                 const u16* __restrict__ xT,
                                                 u16* __restrict__ qT, u16* __restrict__ kT,
                                                 u16* __restrict__ v) {
    int wg = blockIdx.x;                 // [0,640)
    int xcd = wg & 7, slot = wg >> 3;    // slot 0..79
    int b = xcd >> 1;
    int m0 = (slot >> 3) * 64;                       // 10 m-tiles
    int n0 = ((xcd & 1) * 8 + (slot & 7)) * 256;     // 16 n-tiles
    int wave = threadIdx.x >> 6, lane = threadIdx.x & 63;
    n0 += wave * 64;
    int lr = lane & 15, lc = lane >> 4;
    const u16* xTb = xT + (size_t)b * N_ * C_;

    f32x4 acc[4][4] = {};
    short8 aF[4], bF[4], aFn[4], bFn[4];
#pragma unroll
    for (int ma = 0; ma < 4; ma++)
        aF[ma] = *reinterpret_cast<const short8*>(&Wcat[(size_t)(m0 + ma * 16 + lr) * 512 + lc * 8]);
#pragma unroll
    for (int na = 0; na < 4; na++)
        bF[na] = *reinterpret_cast<const short8*>(&xTb[(size_t)(n0 + na * 16 + lr) * 512 + lc * 8]);

    for (int k0 = 0; k0 < 512; k0 += 32) {
        if (k0 < 480) {
            int kn = k0 + 32;
#pragma unroll
            for (int ma = 0; ma < 4; ma++)
                aFn[ma] = *reinterpret_cast<const short8*>(&Wcat[(size_t)(m0 + ma * 16 + lr) * 512 + kn + lc * 8]);
#pragma unroll
            for (int na = 0; na < 4; na++)
                bFn[na] = *reinterpret_cast<const short8*>(&xTb[(size_t)(n0 + na * 16 + lr) * 512 + kn + lc * 8]);
        }
#pragma unroll
        for (int ma = 0; ma < 4; ma++)
#pragma unroll
            for (int na = 0; na < 4; na++)
                acc[ma][na] = MFMA16(aF[ma], bF[na], acc[ma][na]);
#pragma unroll
        for (int t = 0; t < 4; t++) { aF[t] = aFn[t]; bF[t] = bFn[t]; }
    }
#pragma unroll
    for (int ma = 0; ma < 4; ma++) {
#pragma unroll
        for (int r = 0; r < 4; r++) {
            int m = m0 + ma * 16 + lc * 4 + r;
            float bias = biascat[m];
#pragma unroll
            for (int na = 0; na < 4; na++) {
                int n = n0 + na * 16 + lr;
                u16 hv = f2bf(acc[ma][na][r] + bias);
                if (m < 64)
                    qT[((size_t)b * N_ + n) * D_ + m] = hv;
                else if (m < 128)
                    kT[((size_t)b * N_ + n) * D_ + (m - 64)] = hv;
                else {
                    int nl = n & 15;
                    int np = (nl & 3) | ((nl & 4) << 1) | ((nl & 8) >> 1);   // swap j-bits 2<->3
                    v[((size_t)b * C_ + (m - 128)) * (size_t)N_ + (n & ~15) + np] = hv;
                }
            }
        }
    }
}

// ---------------- fused attention: plane-LDS, TILE_J=128, intra-tile jc pipeline ----------------
// 256 blocks x 512 thr (8 waves), 1 block/CU. Wave owns 32 i x 128 c; in-register P
// (swapped mfma32 + cvt_pk, permuted-V pairing); S dup x4 across c-slices.
// R17 delta vs R16: SOFTWARE-PIPELINE jc within the tile -- S(jc+1) issued before
// PV(jc), two named PA sets (PA_A/PA_B, rule-#20-safe): every PV MFMA cluster has an
// independent S chain + exp/pack stream to co-issue with (R16's 4x[S->PV] serialized
// each jc's 4-deep S chain behind the previous PV).
__global__ __launch_bounds__(512, 2) void attn(const u16* __restrict__ qT, const u16* __restrict__ kT,
                                               const u16* __restrict__ v, const float* __restrict__ x,
                                               const float* __restrict__ gamma_p, float* __restrict__ out) {
    int blk = blockIdx.x;               // [0,256)
    int xcd = blk & 7, rest = blk >> 3; // rest in [0,32)
    int b = xcd >> 1;
    int cs = (xcd & 1) + 2 * (rest & 1);    // c-slice 0..3 (XCD L2: 2MB V + 512KB K)
    int itile = rest >> 1;                   // 0..15
    int c0 = cs * 128;
    int ib0 = itile * 256;

    int tid = threadIdx.x;
    int wv = tid >> 6, lane = tid & 63;
    int li = lane & 31, hi = lane >> 5;

    __shared__ char smem[98304];        // 2 x (K 16KB + V 32KB); epilogue reuses

    const u16* qTb = qT + (size_t)b * N_ * D_;
    const u16* kTb = kT + (size_t)b * N_ * D_;
    const u16* vb  = v  + (size_t)b * C_ * N_;

    // Q fragments (B-operand of mfma32: col=li=i, k=hi*8+e), 4 d-chunks of 16
    short8 qf[4];
#pragma unroll
    for (int dc = 0; dc < 4; dc++)
        qf[dc] = *reinterpret_cast<const short8*>(
            &qTb[(size_t)(ib0 + wv * 32 + li) * D_ + dc * 16 + hi * 8]);

    f32x16 acc[4] = {};                 // [ct]: O[i=crow(r,hi)][c=ct*32+li]
    float lsum = 0.f;

    // ---- async staging: 6 loads/wave per 128-j tile (K:2, V:4) ----
    auto STAGE = [&](int t, int buf) {
        int jb = t * 128;
        char* Kb = smem + buf * 49152;
        char* Vb = Kb + 16384;
#pragma unroll
        for (int q = 0; q < 2; q++) {
            int ki = 2 * wv + q;                      // 0..15
            int p = ki >> 1, jh2 = ki & 1;            // K plane p (d-octet), j-half
            gload_lds16(kTb + (size_t)(jb + jh2 * 64 + lane) * D_ + p * 8,
                        Kb + p * 2048 + jh2 * 1024);
        }
#pragma unroll
        for (int q = 0; q < 4; q++) {
            int vi = 4 * wv + q;                      // 0..31
            int qp = vi >> 1, ch = vi & 1;            // V plane qp (j16b,hb), c-half
            int j16b = qp >> 1, hb = qp & 1;
            gload_lds16(vb + (size_t)(c0 + ch * 64 + lane) * N_ + jb + j16b * 16 + hb * 8,
                        Vb + qp * 2048 + ch * 1024);
        }
    };

    // ---- prologue: stage tile 0, drain, barrier ----
    STAGE(0, 0);
    asm volatile("s_waitcnt vmcnt(0)" ::: "memory");
    __builtin_amdgcn_s_barrier();
    asm volatile("" ::: "memory");

    for (int t = 0; t < 32; t++) {
        int buf = t & 1;
        char* Kb = smem + buf * 49152;
        char* Vb = Kb + 16384;

        if (t < 31) STAGE(t + 1, buf ^ 1);   // async; drained at loop bottom

        // ---- S phase for one 32-j chunk: 4 MFMA -> exp -> pack -> PA ----
        auto S_PHASE = [&](int jc, short8* PAo) {
            short8 kf0 = *reinterpret_cast<const short8*>(Kb + (0 + hi) * 2048 + (jc * 32 + li) * 16);
            short8 kf1 = *reinterpret_cast<const short8*>(Kb + (2 + hi) * 2048 + (jc * 32 + li) * 16);
            short8 kf2 = *reinterpret_cast<const short8*>(Kb + (4 + hi) * 2048 + (jc * 32 + li) * 16);
            short8 kf3 = *reinterpret_cast<const short8*>(Kb + (6 + hi) * 2048 + (jc * 32 + li) * 16);
            f32x16 S = {};
            S = MFMA32(kf0, qf[0], S);
            S = MFMA32(kf1, qf[1], S);
            S = MFMA32(kf2, qf[2], S);
            S = MFMA32(kf3, qf[3], S);
            float p[16];
#pragma unroll
            for (int r = 0; r < 16; r++) p[r] = __builtin_amdgcn_exp2f(S[r]);
            lsum += (((p[0]+p[1])+(p[2]+p[3]))+((p[4]+p[5])+(p[6]+p[7])))
                  + (((p[8]+p[9])+(p[10]+p[11]))+((p[12]+p[13])+(p[14]+p[15])));
            u32 w[8];
#pragma unroll
            for (int k = 0; k < 8; k++)
                asm("v_cvt_pk_bf16_f32 %0, %1, %2" : "=v"(w[k]) : "v"(p[2 * k]), "v"(p[2 * k + 1]));
            int4v a0 = { (int)w[0], (int)w[1], (int)w[2], (int)w[3] };
            int4v a1 = { (int)w[4], (int)w[5], (int)w[6], (int)w[7] };
            PAo[0] = __builtin_bit_cast(short8, a0);
            PAo[1] = __builtin_bit_cast(short8, a1);
        };
        // ---- PV phase for one 32-j chunk: 8 MFMA from planes ----
        auto PV_PHASE = [&](int jc, const short8* PAi) {
#pragma unroll
            for (int ct = 0; ct < 4; ct++) {
                short8 vf0 = *reinterpret_cast<const short8*>(
                    Vb + ((jc * 2 + 0) * 2 + hi) * 2048 + (ct * 32 + li) * 16);
                short8 vf1 = *reinterpret_cast<const short8*>(
                    Vb + ((jc * 2 + 1) * 2 + hi) * 2048 + (ct * 32 + li) * 16);
                acc[ct] = MFMA32(PAi[0], vf0, acc[ct]);
                acc[ct] = MFMA32(PAi[1], vf1, acc[ct]);
            }
        };

        // ---- pipelined: S one jc ahead of PV (two named PA sets) ----
        short8 PA_A[2], PA_B[2];
        S_PHASE(0, PA_A);
        S_PHASE(1, PA_B);
        PV_PHASE(0, PA_A);
        S_PHASE(2, PA_A);
        PV_PHASE(1, PA_B);
        S_PHASE(3, PA_B);
        PV_PHASE(2, PA_A);
        PV_PHASE(3, PA_B);

        // ---- drain next tile's async loads, barrier (once per 128 j) ----
        asm volatile("s_waitcnt vmcnt(0)" ::: "memory");
        __builtin_amdgcn_s_barrier();
        asm volatile("" ::: "memory");
    }

    // ---- finalize: row sums, normalize, transpose via per-wave LDS, residual ----
    float lfull = lsum + __shfl_xor(lsum, 32);   // full row-sum for i=li
    float g = gamma_p[0];
    float* olds = reinterpret_cast<float*>(smem + wv * 4608);   // [32 c][36] f32 per wave
    const float* xb = x + (size_t)b * C_ * N_;
    float* ob = out + (size_t)b * C_ * N_;
#pragma unroll
    for (int ct = 0; ct < 4; ct++) {
#pragma unroll
        for (int r = 0; r < 16; r++) {
            int crow = (r & 3) + 8 * (r >> 2) + 4 * hi;     // i-local
            float linv = 1.0f / __shfl(lfull, crow);
            olds[li * 36 + crow] = g * acc[ct][r] * linv;
        }
        asm volatile("s_waitcnt lgkmcnt(0)" ::: "memory");
#pragma unroll
        for (int cp = 0; cp < 4; cp++) {
            int c_l = cp * 8 + (lane >> 3);
            int i4 = (lane & 7) * 4;
            float4 o4 = *reinterpret_cast<const float4*>(&olds[c_l * 36 + i4]);
            size_t off = (size_t)(c0 + ct * 32 + c_l) * N_ + ib0 + wv * 32 + i4;
            float4 xv = *reinterpret_cast<const float4*>(&xb[off]);
            float4 ov = { o4.x + xv.x, o4.y + xv.y, o4.z + xv.z, o4.w + xv.w };
            *reinterpret_cast<float4*>(&ob[off]) = ov;
        }
        asm volatile("s_waitcnt lgkmcnt(0)" ::: "memory");
    }
}

extern "C" void kernel_launch(void* const* d_in, const int* in_sizes, int n_in,
                              void* d_out, int out_size, void* d_ws, size_t ws_size,
                              hipStream_t stream) {
    const float* x     = (const float*)d_in[0];
    const float* Wq    = (const float*)d_in[1];
    const float* bq    = (const float*)d_in[2];
    const float* Wk    = (const float*)d_in[3];
    const float* bk    = (const float*)d_in[4];
    const float* Wv    = (const float*)d_in[5];
    const float* bv    = (const float*)d_in[6];
    const float* gamma = (const float*)d_in[7];
    float* out = (float*)d_out;

    char* ws = (char*)d_ws;
    // layout (bytes): xT 16MB | Wcat 640KB | biascat 4KB | qT 2MB | kT 2MB | v 16MB
    u16*   xT      = (u16*)ws;
    u16*   Wcat    = (u16*)(ws + (size_t)16777216);
    float* biascat = (float*)(ws + (size_t)16777216 + 655360);
    u16*   qT      = (u16*)(ws + (size_t)16777216 + 655360 + 4096);
    u16*   kT      = qT + (size_t)B_ * N_ * D_;
    u16*   v       = kT + (size_t)B_ * N_ * D_;

    prep_and_transpose<<<dim3(N_ / 64, C_ / 64, B_ + 1), 256, 0, stream>>>(
        x, xT, Wq, bq, Wk, bk, Wv, bv, Wcat, biascat);
    proj_gemm<<<640, 256, 0, stream>>>(Wcat, biascat, xT, qT, kT, v);
    attn<<<256, 512, 0, stream>>>(qT, kT, v, x, gamma, out);
}

// Round 18
// 140.341 us; speedup vs baseline: 2.9416x; 1.2052x over previous
//
#include <hip/hip_runtime.h>
#include <stdint.h>

typedef unsigned short u16;
typedef unsigned int u32;
typedef __attribute__((ext_vector_type(8))) short short8;   // 8 bf16 = 4 VGPR
typedef __attribute__((ext_vector_type(4))) short s16x4;
typedef __attribute__((ext_vector_type(4))) float f32x4;
typedef __attribute__((ext_vector_type(16))) float f32x16;
typedef __attribute__((ext_vector_type(4))) int int4v;

#define MFMA16(a,b,c) __builtin_amdgcn_mfma_f32_16x16x32_bf16(a,b,c,0,0,0)
#define MFMA32(a,b,c) __builtin_amdgcn_mfma_f32_32x32x16_bf16(a,b,c,0,0,0)

constexpr int B_ = 4, C_ = 512, N_ = 4096, D_ = 64;  // D_ = CQK = C/8

static __device__ __forceinline__ u16 f2bf(float f) {
    uint32_t u = __builtin_bit_cast(uint32_t, f);
    uint32_t r = (u + 0x7FFFu + ((u >> 16) & 1u)) >> 16;   // RNE
    return (u16)r;
}

// async global->LDS, 16B per lane: dest = lds_base + lane*16 (wave-uniform base),
// src is PER-LANE global address
static __device__ __forceinline__ void gload_lds16(const void* g, void* l) {
    __builtin_amdgcn_global_load_lds(
        (const __attribute__((address_space(1))) u32*)g,
        (__attribute__((address_space(3))) u32*)l, 16, 0, 0);
}

// ---------------- merged: transpose x (z<B) + prep Wcat/biascat (z==B) ----------------
__global__ __launch_bounds__(256) void prep_and_transpose(
        const float* __restrict__ x, u16* __restrict__ xT,
        const float* __restrict__ Wq, const float* __restrict__ bq,
        const float* __restrict__ Wk, const float* __restrict__ bk,
        const float* __restrict__ Wv, const float* __restrict__ bv,
        u16* __restrict__ Wcat, float* __restrict__ biascat) {
    const float LOG2E = 1.44269504088896340736f;
    if (blockIdx.z == B_) {
        int base = (blockIdx.y * 64 + blockIdx.x) * 256 + threadIdx.x;  // 131072 threads
        for (int idx = base; idx < 640 * 512; idx += 64 * 8 * 256) {
            int row = idx >> 9, col = idx & 511;
            float w;
            if (row < 64)        w = Wq[row * 512 + col] * LOG2E;
            else if (row < 128)  w = Wk[(row - 64) * 512 + col];
            else                 w = Wv[(row - 128) * 512 + col];
            Wcat[idx] = f2bf(w);
        }
        if (base < 640) {
            float bb;
            if (base < 64)       bb = bq[base] * LOG2E;
            else if (base < 128) bb = bk[base - 64];
            else                 bb = bv[base - 128];
            biascat[base] = bb;
        }
        return;
    }
    __shared__ float tile[64][65];
    int n0 = blockIdx.x * 64, c0 = blockIdx.y * 64, b = blockIdx.z;
    int t = threadIdx.x;
    int colq = (t & 15) * 4, rowb = t >> 4;      // rowb 0..15
    const float* xb = x + (size_t)b * C_ * N_;
#pragma unroll
    for (int k = 0; k < 4; k++) {
        int row = rowb + 16 * k;                 // c-row
        float4 xv = *reinterpret_cast<const float4*>(&xb[(size_t)(c0 + row) * N_ + n0 + colq]);
        tile[row][colq + 0] = xv.x;
        tile[row][colq + 1] = xv.y;
        tile[row][colq + 2] = xv.z;
        tile[row][colq + 3] = xv.w;
    }
    __syncthreads();
    u16* xTb = xT + (size_t)b * N_ * C_;
#pragma unroll
    for (int k = 0; k < 4; k++) {
        int n = rowb + 16 * k;
        ushort4 o;
        o.x = f2bf(tile[colq + 0][n]);
        o.y = f2bf(tile[colq + 1][n]);
        o.z = f2bf(tile[colq + 2][n]);
        o.w = f2bf(tile[colq + 3][n]);
        *reinterpret_cast<ushort4*>(&xTb[(size_t)(n0 + n) * C_ + c0 + colq]) = o;
    }
}

// ---------------- projection GEMM, m97-structure: 128x128 tile, BK=32, LDS dbuf ----------------
// R18: replaces the direct-global-load loop (~300 GF/s) with the proven ladder structure:
// global_load_lds(16B) staging into double-buffered LDS [128][32] bf16 tiles, ds_read_b128
// fragments, 16 MFMA16 per wave per K-step, vmcnt(0)+barrier once per step (874 TF on the
// learn_hip ladder at this shape). Epilogue unchanged: bias + qT/kT scatter + v stored with
// per-16 j-permutation (swap bits 2<->3 of j&15) for attention's contiguous PV fragments.
__global__ __launch_bounds__(256) void proj_gemm(const u16* __restrict__ Wcat,
                                                 const float* __restrict__ biascat,
                                                 const u16* __restrict__ xT,
                                                 u16* __restrict__ qT, u16* __restrict__ kT,
                                                 u16* __restrict__ v) {
    int wg = blockIdx.x;                 // [0,640)
    int xcd = wg & 7, slot = wg >> 3;    // slot 0..79
    int b = xcd >> 1;
    int m0 = (slot >> 4) * 128;                      // 5 m-tiles (M=640)
    int n0 = ((xcd & 1) * 16 + (slot & 15)) * 128;   // 32 n-tiles
    int wave = threadIdx.x >> 6, lane = threadIdx.x & 63;
    int lr = lane & 15, lc = lane >> 4;
    int wm = (wave & 1) * 64, wn = (wave >> 1) * 64;  // wave's 64x64 quadrant
    const u16* xTb = xT + (size_t)b * N_ * C_;

    __shared__ u16 Ab[2][128 * 32];     // [m][k] row-major, 64B rows
    __shared__ u16 Bb[2][128 * 32];     // [n][k]

    // stage one 128x32 A-tile + B-tile chunk pair per wave (8 chunks each, 2/wave)
    auto STAGE = [&](int ks, int buf) {
        int k0 = ks * 32;
        int row = lane >> 2, co = (lane & 3) * 8;    // 16 rows/chunk, 4 lanes/row
#pragma unroll
        for (int q = 0; q < 2; q++) {
            int ch = 2 * wave + q;                   // 0..7
            gload_lds16(&Wcat[(size_t)(m0 + ch * 16 + row) * 512 + k0 + co],
                        (char*)Ab[buf] + ch * 1024);
            gload_lds16(&xTb[(size_t)(n0 + ch * 16 + row) * 512 + k0 + co],
                        (char*)Bb[buf] + ch * 1024);
        }
    };

    f32x4 acc[4][4] = {};   // [ma][na]

    STAGE(0, 0);
    asm volatile("s_waitcnt vmcnt(0)" ::: "memory");
    __builtin_amdgcn_s_barrier();
    asm volatile("" ::: "memory");

    for (int ks = 0; ks < 16; ks++) {
        int buf = ks & 1;
        if (ks < 15) STAGE(ks + 1, buf ^ 1);

        short8 aF[4], bF[4];
#pragma unroll
        for (int t = 0; t < 4; t++) {
            aF[t] = *reinterpret_cast<const short8*>(
                (const char*)Ab[buf] + (wm + t * 16 + lr) * 64 + lc * 16);
            bF[t] = *reinterpret_cast<const short8*>(
                (const char*)Bb[buf] + (wn + t * 16 + lr) * 64 + lc * 16);
        }
#pragma unroll
        for (int ma = 0; ma < 4; ma++)
#pragma unroll
            for (int na = 0; na < 4; na++)
                acc[ma][na] = MFMA16(aF[ma], bF[na], acc[ma][na]);

        asm volatile("s_waitcnt vmcnt(0)" ::: "memory");
        __builtin_amdgcn_s_barrier();
        asm volatile("" ::: "memory");
    }

    // epilogue: bias + scatter (qT/kT n-major, v c-major with j-permutation)
#pragma unroll
    for (int ma = 0; ma < 4; ma++) {
#pragma unroll
        for (int r = 0; r < 4; r++) {
            int m = m0 + wm + ma * 16 + lc * 4 + r;
            float bias = biascat[m];
#pragma unroll
            for (int na = 0; na < 4; na++) {
                int n = n0 + wn + na * 16 + lr;
                u16 hv = f2bf(acc[ma][na][r] + bias);
                if (m < 64)
                    qT[((size_t)b * N_ + n) * D_ + m] = hv;
                else if (m < 128)
                    kT[((size_t)b * N_ + n) * D_ + (m - 64)] = hv;
                else {
                    int nl = n & 15;
                    int np = (nl & 3) | ((nl & 4) << 1) | ((nl & 8) >> 1);   // swap j-bits 2<->3
                    v[((size_t)b * C_ + (m - 128)) * (size_t)N_ + (n & ~15) + np] = hv;
                }
            }
        }
    }
}

// ---------------- fused attention: plane-LDS, TILE_J=128 (R17, unchanged: 115us verified) ----------------
__global__ __launch_bounds__(512, 2) void attn(const u16* __restrict__ qT, const u16* __restrict__ kT,
                                               const u16* __restrict__ v, const float* __restrict__ x,
                                               const float* __restrict__ gamma_p, float* __restrict__ out) {
    int blk = blockIdx.x;               // [0,256)
    int xcd = blk & 7, rest = blk >> 3; // rest in [0,32)
    int b = xcd >> 1;
    int cs = (xcd & 1) + 2 * (rest & 1);    // c-slice 0..3 (XCD L2: 2MB V + 512KB K)
    int itile = rest >> 1;                   // 0..15
    int c0 = cs * 128;
    int ib0 = itile * 256;

    int tid = threadIdx.x;
    int wv = tid >> 6, lane = tid & 63;
    int li = lane & 31, hi = lane >> 5;

    __shared__ char smem[98304];        // 2 x (K 16KB + V 32KB); epilogue reuses

    const u16* qTb = qT + (size_t)b * N_ * D_;
    const u16* kTb = kT + (size_t)b * N_ * D_;
    const u16* vb  = v  + (size_t)b * C_ * N_;

    // Q fragments (B-operand of mfma32: col=li=i, k=hi*8+e), 4 d-chunks of 16
    short8 qf[4];
#pragma unroll
    for (int dc = 0; dc < 4; dc++)
        qf[dc] = *reinterpret_cast<const short8*>(
            &qTb[(size_t)(ib0 + wv * 32 + li) * D_ + dc * 16 + hi * 8]);

    f32x16 acc[4] = {};                 // [ct]: O[i=crow(r,hi)][c=ct*32+li]
    float lsum = 0.f;

    // ---- async staging: 6 loads/wave per 128-j tile (K:2, V:4) ----
    auto STAGE = [&](int t, int buf) {
        int jb = t * 128;
        char* Kb = smem + buf * 49152;
        char* Vb = Kb + 16384;
#pragma unroll
        for (int q = 0; q < 2; q++) {
            int ki = 2 * wv + q;                      // 0..15
            int p = ki >> 1, jh2 = ki & 1;            // K plane p (d-octet), j-half
            gload_lds16(kTb + (size_t)(jb + jh2 * 64 + lane) * D_ + p * 8,
                        Kb + p * 2048 + jh2 * 1024);
        }
#pragma unroll
        for (int q = 0; q < 4; q++) {
            int vi = 4 * wv + q;                      // 0..31
            int qp = vi >> 1, ch = vi & 1;            // V plane qp (j16b,hb), c-half
            int j16b = qp >> 1, hb = qp & 1;
            gload_lds16(vb + (size_t)(c0 + ch * 64 + lane) * N_ + jb + j16b * 16 + hb * 8,
                        Vb + qp * 2048 + ch * 1024);
        }
    };

    // ---- prologue: stage tile 0, drain, barrier ----
    STAGE(0, 0);
    asm volatile("s_waitcnt vmcnt(0)" ::: "memory");
    __builtin_amdgcn_s_barrier();
    asm volatile("" ::: "memory");

    for (int t = 0; t < 32; t++) {
        int buf = t & 1;
        char* Kb = smem + buf * 49152;
        char* Vb = Kb + 16384;

        if (t < 31) STAGE(t + 1, buf ^ 1);   // async; drained at loop bottom

        auto S_PHASE = [&](int jc, short8* PAo) {
            short8 kf0 = *reinterpret_cast<const short8*>(Kb + (0 + hi) * 2048 + (jc * 32 + li) * 16);
            short8 kf1 = *reinterpret_cast<const short8*>(Kb + (2 + hi) * 2048 + (jc * 32 + li) * 16);
            short8 kf2 = *reinterpret_cast<const short8*>(Kb + (4 + hi) * 2048 + (jc * 32 + li) * 16);
            short8 kf3 = *reinterpret_cast<const short8*>(Kb + (6 + hi) * 2048 + (jc * 32 + li) * 16);
            f32x16 S = {};
            S = MFMA32(kf0, qf[0], S);
            S = MFMA32(kf1, qf[1], S);
            S = MFMA32(kf2, qf[2], S);
            S = MFMA32(kf3, qf[3], S);
            float p[16];
#pragma unroll
            for (int r = 0; r < 16; r++) p[r] = __builtin_amdgcn_exp2f(S[r]);
            lsum += (((p[0]+p[1])+(p[2]+p[3]))+((p[4]+p[5])+(p[6]+p[7])))
                  + (((p[8]+p[9])+(p[10]+p[11]))+((p[12]+p[13])+(p[14]+p[15])));
            u32 w[8];
#pragma unroll
            for (int k = 0; k < 8; k++)
                asm("v_cvt_pk_bf16_f32 %0, %1, %2" : "=v"(w[k]) : "v"(p[2 * k]), "v"(p[2 * k + 1]));
            int4v a0 = { (int)w[0], (int)w[1], (int)w[2], (int)w[3] };
            int4v a1 = { (int)w[4], (int)w[5], (int)w[6], (int)w[7] };
            PAo[0] = __builtin_bit_cast(short8, a0);
            PAo[1] = __builtin_bit_cast(short8, a1);
        };
        auto PV_PHASE = [&](int jc, const short8* PAi) {
#pragma unroll
            for (int ct = 0; ct < 4; ct++) {
                short8 vf0 = *reinterpret_cast<const short8*>(
                    Vb + ((jc * 2 + 0) * 2 + hi) * 2048 + (ct * 32 + li) * 16);
                short8 vf1 = *reinterpret_cast<const short8*>(
                    Vb + ((jc * 2 + 1) * 2 + hi) * 2048 + (ct * 32 + li) * 16);
                acc[ct] = MFMA32(PAi[0], vf0, acc[ct]);
                acc[ct] = MFMA32(PAi[1], vf1, acc[ct]);
            }
        };

        short8 PA_A[2], PA_B[2];
        S_PHASE(0, PA_A);
        S_PHASE(1, PA_B);
        PV_PHASE(0, PA_A);
        S_PHASE(2, PA_A);
        PV_PHASE(1, PA_B);
        S_PHASE(3, PA_B);
        PV_PHASE(2, PA_A);
        PV_PHASE(3, PA_B);

        asm volatile("s_waitcnt vmcnt(0)" ::: "memory");
        __builtin_amdgcn_s_barrier();
        asm volatile("" ::: "memory");
    }

    // ---- finalize: row sums, normalize, transpose via per-wave LDS, residual ----
    float lfull = lsum + __shfl_xor(lsum, 32);   // full row-sum for i=li
    float g = gamma_p[0];
    float* olds = reinterpret_cast<float*>(smem + wv * 4608);   // [32 c][36] f32 per wave
    const float* xb = x + (size_t)b * C_ * N_;
    float* ob = out + (size_t)b * C_ * N_;
#pragma unroll
    for (int ct = 0; ct < 4; ct++) {
#pragma unroll
        for (int r = 0; r < 16; r++) {
            int crow = (r & 3) + 8 * (r >> 2) + 4 * hi;     // i-local
            float linv = 1.0f / __shfl(lfull, crow);
            olds[li * 36 + crow] = g * acc[ct][r] * linv;
        }
        asm volatile("s_waitcnt lgkmcnt(0)" ::: "memory");
#pragma unroll
        for (int cp = 0; cp < 4; cp++) {
            int c_l = cp * 8 + (lane >> 3);
            int i4 = (lane & 7) * 4;
            float4 o4 = *reinterpret_cast<const float4*>(&olds[c_l * 36 + i4]);
            size_t off = (size_t)(c0 + ct * 32 + c_l) * N_ + ib0 + wv * 32 + i4;
            float4 xv = *reinterpret_cast<const float4*>(&xb[off]);
            float4 ov = { o4.x + xv.x, o4.y + xv.y, o4.z + xv.z, o4.w + xv.w };
            *reinterpret_cast<float4*>(&ob[off]) = ov;
        }
        asm volatile("s_waitcnt lgkmcnt(0)" ::: "memory");
    }
}

extern "C" void kernel_launch(void* const* d_in, const int* in_sizes, int n_in,
                              void* d_out, int out_size, void* d_ws, size_t ws_size,
                              hipStream_t stream) {
    const float* x     = (const float*)d_in[0];
    const float* Wq    = (const float*)d_in[1];
    const float* bq    = (const float*)d_in[2];
    const float* Wk    = (const float*)d_in[3];
    const float* bk    = (const float*)d_in[4];
    const float* Wv    = (const float*)d_in[5];
    const float* bv    = (const float*)d_in[6];
    const float* gamma = (const float*)d_in[7];
    float* out = (float*)d_out;

    char* ws = (char*)d_ws;
    // layout (bytes): xT 16MB | Wcat 640KB | biascat 4KB | qT 2MB | kT 2MB | v 16MB
    u16*   xT      = (u16*)ws;
    u16*   Wcat    = (u16*)(ws + (size_t)16777216);
    float* biascat = (float*)(ws + (size_t)16777216 + 655360);
    u16*   qT      = (u16*)(ws + (size_t)16777216 + 655360 + 4096);
    u16*   kT      = qT + (size_t)B_ * N_ * D_;
    u16*   v       = kT + (size_t)B_ * N_ * D_;

    prep_and_transpose<<<dim3(N_ / 64, C_ / 64, B_ + 1), 256, 0, stream>>>(
        x, xT, Wq, bq, Wk, bk, Wv, bv, Wcat, biascat);
    proj_gemm<<<640, 256, 0, stream>>>(Wcat, biascat, xT, qT, kT, v);
    attn<<<256, 512, 0, stream>>>(qT, kT, v, x, gamma, out);
}